// Round 1
// baseline (12844.775 us; speedup 1.0000x reference)
//
#include <hip/hip_runtime.h>
#include <hip/hip_bf16.h>

// Problem constants
#define S_LEN 256
#define NBATCH 64
#define EMBD 1024
#define HIDD 1024
#define G4 4096      // 4*HID
#define CHUNK 64     // timesteps per xproj chunk
#define KSLICE 4     // K-slices in recurrent gemm

// ---------------------------------------------------------------------------
// inproj_gemm: out[m][g] = sum_k A[row(m)][k] * W[g][k] + b1[g] + b2[g]
//   A rows: if idx != nullptr, row = idx[mbase+m] (embedding gather), else
//   row = mbase+m (direct, layer-1 input = ys0).
//   M-tile/N-tile = 64x64, BK = 32, 256 threads, 4x4 acc per thread.
// ---------------------------------------------------------------------------
__global__ __launch_bounds__(256) void inproj_gemm(
    const float* __restrict__ A, const int* __restrict__ idx,
    const float* __restrict__ W, const float* __restrict__ b1,
    const float* __restrict__ b2, float* __restrict__ out, int mbase)
{
    __shared__ __align__(16) float As[32][68];
    __shared__ __align__(16) float Bs[32][68];
    const int t  = threadIdx.x;
    const int n0 = blockIdx.x * 64;
    const int m0 = blockIdx.y * 64;
    const int tx = t & 15, ty = t >> 4;
    const int lr = t >> 2;          // 0..63 tile row for loads
    const int lk = (t & 3) * 8;     // 0,8,16,24 k-offset for loads

    const int mg = mbase + m0 + lr;
    const float* arow = idx ? (A + (size_t)idx[mg] * 1024u)
                            : (A + (size_t)mg * 1024u);
    const float* brow = W + (size_t)(n0 + lr) * 1024u;

    float acc[4][4] = {{0.f,0.f,0.f,0.f},{0.f,0.f,0.f,0.f},
                       {0.f,0.f,0.f,0.f},{0.f,0.f,0.f,0.f}};

    for (int k0 = 0; k0 < 1024; k0 += 32) {
        const float4 a0  = *(const float4*)(arow + k0 + lk);
        const float4 a1  = *(const float4*)(arow + k0 + lk + 4);
        const float4 bb0 = *(const float4*)(brow + k0 + lk);
        const float4 bb1 = *(const float4*)(brow + k0 + lk + 4);
        __syncthreads();
        As[lk+0][lr]=a0.x;  As[lk+1][lr]=a0.y;  As[lk+2][lr]=a0.z;  As[lk+3][lr]=a0.w;
        As[lk+4][lr]=a1.x;  As[lk+5][lr]=a1.y;  As[lk+6][lr]=a1.z;  As[lk+7][lr]=a1.w;
        Bs[lk+0][lr]=bb0.x; Bs[lk+1][lr]=bb0.y; Bs[lk+2][lr]=bb0.z; Bs[lk+3][lr]=bb0.w;
        Bs[lk+4][lr]=bb1.x; Bs[lk+5][lr]=bb1.y; Bs[lk+6][lr]=bb1.z; Bs[lk+7][lr]=bb1.w;
        __syncthreads();
        #pragma unroll
        for (int kk = 0; kk < 32; ++kk) {
            const float4 av = *(const float4*)&As[kk][ty*4];
            const float4 bv = *(const float4*)&Bs[kk][tx*4];
            acc[0][0] += av.x*bv.x; acc[0][1] += av.x*bv.y;
            acc[0][2] += av.x*bv.z; acc[0][3] += av.x*bv.w;
            acc[1][0] += av.y*bv.x; acc[1][1] += av.y*bv.y;
            acc[1][2] += av.y*bv.z; acc[1][3] += av.y*bv.w;
            acc[2][0] += av.z*bv.x; acc[2][1] += av.z*bv.y;
            acc[2][2] += av.z*bv.z; acc[2][3] += av.z*bv.w;
            acc[3][0] += av.w*bv.x; acc[3][1] += av.w*bv.y;
            acc[3][2] += av.w*bv.z; acc[3][3] += av.w*bv.w;
        }
    }
    #pragma unroll
    for (int i = 0; i < 4; ++i) {
        #pragma unroll
        for (int j = 0; j < 4; ++j) {
            const int g = n0 + tx*4 + j;
            out[(size_t)(m0 + ty*4 + i) * 4096u + g] = acc[i][j] + b1[g] + b2[g];
        }
    }
}

// ---------------------------------------------------------------------------
// rnn_gemm: partial[ks][b][g] = sum_{k in slice ks} h[b][k] * Whh[g][k]
//   grid = (G4/64, KSLICE). Same 64x64 tile structure, K-slice of 256.
// ---------------------------------------------------------------------------
__global__ __launch_bounds__(256) void rnn_gemm(
    const float* __restrict__ h, const float* __restrict__ Whh,
    float* __restrict__ partial)
{
    __shared__ __align__(16) float As[32][68];
    __shared__ __align__(16) float Bs[32][68];
    const int t  = threadIdx.x;
    const int n0 = blockIdx.x * 64;
    const int ks = blockIdx.y;
    const int kb = ks * 256;
    const int tx = t & 15, ty = t >> 4;
    const int lr = t >> 2;
    const int lk = (t & 3) * 8;

    const float* arow = h   + (size_t)lr * 1024u;          // batch row
    const float* brow = Whh + (size_t)(n0 + lr) * 1024u;   // gate row

    float acc[4][4] = {{0.f,0.f,0.f,0.f},{0.f,0.f,0.f,0.f},
                       {0.f,0.f,0.f,0.f},{0.f,0.f,0.f,0.f}};

    for (int k0 = kb; k0 < kb + 256; k0 += 32) {
        const float4 a0  = *(const float4*)(arow + k0 + lk);
        const float4 a1  = *(const float4*)(arow + k0 + lk + 4);
        const float4 bb0 = *(const float4*)(brow + k0 + lk);
        const float4 bb1 = *(const float4*)(brow + k0 + lk + 4);
        __syncthreads();
        As[lk+0][lr]=a0.x;  As[lk+1][lr]=a0.y;  As[lk+2][lr]=a0.z;  As[lk+3][lr]=a0.w;
        As[lk+4][lr]=a1.x;  As[lk+5][lr]=a1.y;  As[lk+6][lr]=a1.z;  As[lk+7][lr]=a1.w;
        Bs[lk+0][lr]=bb0.x; Bs[lk+1][lr]=bb0.y; Bs[lk+2][lr]=bb0.z; Bs[lk+3][lr]=bb0.w;
        Bs[lk+4][lr]=bb1.x; Bs[lk+5][lr]=bb1.y; Bs[lk+6][lr]=bb1.z; Bs[lk+7][lr]=bb1.w;
        __syncthreads();
        #pragma unroll
        for (int kk = 0; kk < 32; ++kk) {
            const float4 av = *(const float4*)&As[kk][ty*4];
            const float4 bv = *(const float4*)&Bs[kk][tx*4];
            acc[0][0] += av.x*bv.x; acc[0][1] += av.x*bv.y;
            acc[0][2] += av.x*bv.z; acc[0][3] += av.x*bv.w;
            acc[1][0] += av.y*bv.x; acc[1][1] += av.y*bv.y;
            acc[1][2] += av.y*bv.z; acc[1][3] += av.y*bv.w;
            acc[2][0] += av.z*bv.x; acc[2][1] += av.z*bv.y;
            acc[2][2] += av.z*bv.z; acc[2][3] += av.z*bv.w;
            acc[3][0] += av.w*bv.x; acc[3][1] += av.w*bv.y;
            acc[3][2] += av.w*bv.z; acc[3][3] += av.w*bv.w;
        }
    }
    float* prow = partial + (size_t)ks * 64u * 4096u;
    #pragma unroll
    for (int i = 0; i < 4; ++i) {
        #pragma unroll
        for (int j = 0; j < 4; ++j) {
            prow[(size_t)(ty*4 + i) * 4096u + n0 + tx*4 + j] = acc[i][j];
        }
    }
}

// ---------------------------------------------------------------------------
// rnn_pointwise: gates = xp + sum_ks partial; i,f,g,o split; update c,h.
//   64*1024 threads; tid = b*1024 + hc.
// ---------------------------------------------------------------------------
__global__ __launch_bounds__(256) void rnn_pointwise(
    const float* __restrict__ xp,        // [64][4096] for this timestep
    const float* __restrict__ partial,   // [KSLICE][64][4096]
    float* __restrict__ hbuf, float* __restrict__ cbuf,
    float* __restrict__ ys, int tglob)
{
    const int tid = blockIdx.x * 256 + threadIdx.x;  // 0..65535
    const int b  = tid >> 10;
    const int hc = tid & 1023;
    float s[4];
    #pragma unroll
    for (int q = 0; q < 4; ++q) {
        const int g = q * 1024 + hc;
        float v = xp[(size_t)b * 4096u + g];
        #pragma unroll
        for (int ks = 0; ks < KSLICE; ++ks)
            v += partial[(size_t)(ks * 64 + b) * 4096u + g];
        s[q] = v;
    }
    const float ig = 1.f / (1.f + __expf(-s[0]));
    const float fg = 1.f / (1.f + __expf(-s[1]));
    const float gg = tanhf(s[2]);
    const float og = 1.f / (1.f + __expf(-s[3]));
    const float c  = fg * cbuf[tid] + ig * gg;
    const float h  = og * tanhf(c);
    cbuf[tid] = c;
    hbuf[tid] = h;
    if (ys) ys[(size_t)tglob * 65536u + tid] = h;
}

// ---------------------------------------------------------------------------
// copy_out: ws h/c region (h0,c0,h1,c1) -> d_out (h0,h1,c0,c1)
// ---------------------------------------------------------------------------
__global__ __launch_bounds__(256) void copy_out(
    const float* __restrict__ hcbuf, float* __restrict__ out)
{
    const int i = blockIdx.x * 256 + threadIdx.x;  // 0..262143
    const int sec = i >> 16, off = i & 65535;
    const int src_sec = (sec == 0) ? 0 : (sec == 1) ? 2 : (sec == 2) ? 1 : 3;
    out[i] = hcbuf[(src_sec << 16) + off];
}

// ---------------------------------------------------------------------------
extern "C" void kernel_launch(void* const* d_in, const int* in_sizes, int n_in,
                              void* d_out, int out_size, void* d_ws, size_t ws_size,
                              hipStream_t stream) {
    (void)in_sizes; (void)n_in; (void)out_size; (void)ws_size;
    const int*   idx  = (const int*)d_in[0];
    const float* emb  = (const float*)d_in[1];
    const float* wih[2] = {(const float*)d_in[2], (const float*)d_in[6]};
    const float* whh[2] = {(const float*)d_in[3], (const float*)d_in[7]};
    const float* bih[2] = {(const float*)d_in[4], (const float*)d_in[8]};
    const float* bhh[2] = {(const float*)d_in[5], (const float*)d_in[9]};
    float* out = (float*)d_out;

    // ws layout (floats):
    //   [0)        h0,c0,h1,c1 : 4 * 65536 = 262144
    //   [262144)   partial     : 4 * 64 * 4096 = 1048576
    //   [1310720)  xproj chunk : 64 * 64 * 4096 = 16777216
    //   [18087936) ys0         : 256 * 64 * 1024 = 16777216
    float* ws    = (float*)d_ws;
    float* hc    = ws;
    float* part  = ws + 262144;
    float* xproj = ws + 1310720;
    float* ys0   = ws + 18087936;

    // zero-init h,c (ws is re-poisoned before every call)
    hipMemsetAsync(hc, 0, 262144 * sizeof(float), stream);

    for (int L = 0; L < 2; ++L) {
        const float* Abase = (L == 0) ? emb : ys0;
        const int*   gidx  = (L == 0) ? idx : nullptr;
        float* hbuf = hc + (L ? 131072 : 0);
        float* cbuf = hc + (L ? 196608 : 65536);
        float* ysout = (L == 0) ? ys0 : nullptr;
        for (int ch = 0; ch < 4; ++ch) {
            inproj_gemm<<<dim3(64, 64), 256, 0, stream>>>(
                Abase, gidx, wih[L], bih[L], bhh[L], xproj, ch * 4096);
            for (int tl = 0; tl < CHUNK; ++tl) {
                const int t = ch * CHUNK + tl;
                rnn_gemm<<<dim3(64, KSLICE), 256, 0, stream>>>(hbuf, whh[L], part);
                rnn_pointwise<<<dim3(256), 256, 0, stream>>>(
                    xproj + (size_t)tl * 262144u, part, hbuf, cbuf, ysout, t);
            }
        }
    }
    copy_out<<<dim3(1024), 256, 0, stream>>>(hc, out);
}

// Round 2
// 10942.034 us; speedup vs baseline: 1.1739x; 1.1739x over previous
//
#include <hip/hip_runtime.h>
#include <hip/hip_bf16.h>

typedef __attribute__((ext_vector_type(8))) short bf16x8;
typedef __attribute__((ext_vector_type(4))) float f32x4;

__device__ __forceinline__ ushort f2b(float f) {
    union { float f; unsigned u; } v; v.f = f;
    unsigned r = v.u + 0x7FFFu + ((v.u >> 16) & 1u);
    return (ushort)(r >> 16);
}
__device__ __forceinline__ float b2f(ushort u) {
    union { unsigned u; float f; } v; v.u = ((unsigned)u) << 16;
    return v.f;
}
__device__ __forceinline__ float sigm(float x) {
    return 1.f / (1.f + __expf(-x));
}

// ---------------------------------------------------------------------------
// prep_weights: f32 -> bf16 weight conversion + bias sum (b_ih + b_hh).
// grid 4096 x 256; thread i handles 4 consecutive elements of each matrix.
// ---------------------------------------------------------------------------
__global__ __launch_bounds__(256) void prep_weights(
    const float* __restrict__ wih0, const float* __restrict__ whh0,
    const float* __restrict__ bih0, const float* __restrict__ bhh0,
    const float* __restrict__ wih1, const float* __restrict__ whh1,
    const float* __restrict__ bih1, const float* __restrict__ bhh1,
    ushort* __restrict__ wih0b, ushort* __restrict__ whh0b,
    ushort* __restrict__ wih1b, ushort* __restrict__ whh1b,
    float* __restrict__ bsum0, float* __restrict__ bsum1)
{
    const int i = blockIdx.x * 256 + threadIdx.x;
    const int e = i * 4;
    float4 v;
    v = *(const float4*)&wih0[e];
    *(ushort4*)&wih0b[e] = make_ushort4(f2b(v.x), f2b(v.y), f2b(v.z), f2b(v.w));
    v = *(const float4*)&whh0[e];
    *(ushort4*)&whh0b[e] = make_ushort4(f2b(v.x), f2b(v.y), f2b(v.z), f2b(v.w));
    v = *(const float4*)&wih1[e];
    *(ushort4*)&wih1b[e] = make_ushort4(f2b(v.x), f2b(v.y), f2b(v.z), f2b(v.w));
    v = *(const float4*)&whh1[e];
    *(ushort4*)&whh1b[e] = make_ushort4(f2b(v.x), f2b(v.y), f2b(v.z), f2b(v.w));
    if (i < 1024) {
        const int b4 = i * 4;
        float4 a0 = *(const float4*)&bih0[b4];
        float4 b0 = *(const float4*)&bhh0[b4];
        *(float4*)&bsum0[b4] = make_float4(a0.x + b0.x, a0.y + b0.y, a0.z + b0.z, a0.w + b0.w);
        float4 a1 = *(const float4*)&bih1[b4];
        float4 b1 = *(const float4*)&bhh1[b4];
        *(float4*)&bsum1[b4] = make_float4(a1.x + b1.x, a1.y + b1.y, a1.z + b1.z, a1.w + b1.w);
    }
}

// ---------------------------------------------------------------------------
// gather_x: xg[row][:] = bf16(emb[idx[row]][:]); row = t*64+b, 16384 rows.
// ---------------------------------------------------------------------------
__global__ __launch_bounds__(256) void gather_x(
    const int* __restrict__ idx, const float* __restrict__ emb,
    ushort* __restrict__ xg)
{
    const int row = blockIdx.x;
    const int c = threadIdx.x;
    const int v = idx[row];
    const float4 f = *(const float4*)&emb[(size_t)v * 1024u + c * 4];
    *(ushort4*)&xg[(size_t)row * 1024u + c * 4] =
        make_ushort4(f2b(f.x), f2b(f.y), f2b(f.z), f2b(f.w));
}

// ---------------------------------------------------------------------------
// inproj_mfma: xp[m][g] = sum_k A[mbase+m][k]*W[g][k] + bsum[g]   (bf16 out)
// 128x128 tile, 256 thr = 4 waves, each wave 64x64 (4x4 of 16x16x32 MFMA).
// A rows are pre-gathered bf16 (xg or ys0). LDS rows padded +8 bf16 (2-way max).
// ---------------------------------------------------------------------------
__global__ __launch_bounds__(256) void inproj_mfma(
    const ushort* __restrict__ A, const ushort* __restrict__ W,
    const float* __restrict__ bsum, ushort* __restrict__ xpout, int mbase)
{
    __shared__ ushort As[128][72];
    __shared__ ushort Bsh[128][72];
    const int tid = threadIdx.x;
    const int wv = tid >> 6, lane = tid & 63;
    const int l15 = lane & 15, l4 = lane >> 4;
    const int m0 = blockIdx.y * 128, n0 = blockIdx.x * 128;
    const int wm = (wv & 1) * 64, wn = (wv >> 1) * 64;

    f32x4 acc[4][4];
    #pragma unroll
    for (int i = 0; i < 4; ++i)
        #pragma unroll
        for (int j = 0; j < 4; ++j) acc[i][j] = (f32x4){0.f, 0.f, 0.f, 0.f};

    for (int k0 = 0; k0 < 1024; k0 += 64) {
        __syncthreads();
        #pragma unroll
        for (int s4 = 0; s4 < 4; ++s4) {
            const int s = tid + s4 * 256;
            const int row = s >> 3, c8 = (s & 7) * 8;
            *(bf16x8*)&As[row][c8] =
                *(const bf16x8*)&A[(size_t)(mbase + m0 + row) * 1024u + k0 + c8];
            *(bf16x8*)&Bsh[row][c8] =
                *(const bf16x8*)&W[(size_t)(n0 + row) * 1024u + k0 + c8];
        }
        __syncthreads();
        #pragma unroll
        for (int kk = 0; kk < 2; ++kk) {
            bf16x8 af[4], bfr[4];
            #pragma unroll
            for (int i = 0; i < 4; ++i) {
                af[i]  = *(const bf16x8*)&As[wm + i * 16 + l15][kk * 32 + l4 * 8];
                bfr[i] = *(const bf16x8*)&Bsh[wn + i * 16 + l15][kk * 32 + l4 * 8];
            }
            #pragma unroll
            for (int i = 0; i < 4; ++i)
                #pragma unroll
                for (int j = 0; j < 4; ++j)
                    acc[i][j] = __builtin_amdgcn_mfma_f32_16x16x32_bf16(
                        af[i], bfr[j], acc[i][j], 0, 0, 0);
        }
    }
    #pragma unroll
    for (int i = 0; i < 4; ++i) {
        const int m = m0 + wm + i * 16 + l4 * 4;
        #pragma unroll
        for (int j = 0; j < 4; ++j) {
            const int g = n0 + wn + j * 16 + l15;
            const float bs = bsum[g];
            #pragma unroll
            for (int r = 0; r < 4; ++r)
                xpout[(size_t)(m + r) * 4096u + g] = f2b(acc[i][j][r] + bs);
        }
    }
}

// ---------------------------------------------------------------------------
// lstm_persist: NT timesteps of one LSTM layer in ONE launch.
// 64 blocks x 512 thr (8 waves). Block owns hc in [blk*16, blk*16+16) i.e.
// gates q*1024+hc for q=0..3. Wave w: bt=w&3 (16 batch rows), kh=w>>2 (K half).
// Gates = xp (precomputed, has bias) + h @ Whh^T via 16x16x32 bf16 MFMA.
// Quadrants 0,1 weights staged in LDS once; 2,3 streamed from L2.
// c state in registers; h double-buffered in global; 1 grid barrier/step.
// ---------------------------------------------------------------------------
__global__ __launch_bounds__(512) void lstm_persist(
    const ushort* __restrict__ Whh,   // bf16 [4096][1024]
    const ushort* __restrict__ xp,    // bf16 [NT*64][4096] chunk-local rows
    ushort* __restrict__ hbuf,        // bf16 [2][64][1024] ping-pong
    float* __restrict__ cbuf,         // f32 [64][1024] chunk-boundary c
    ushort* __restrict__ ys,          // bf16 [16384][1024] or null
    float* __restrict__ outHC,        // d_out: h0,h1,c0,c1 each 64x1024 f32
    unsigned* __restrict__ bar,       // [0]=cnt [1]=gen
    int t0, int nt, int layer)
{
    __shared__ ushort Bs[32][1032];   // quadrants 0,1: rows q*16+j
    __shared__ float red[4][64][18];
    const int tid = threadIdx.x;
    const int wv = tid >> 6, lane = tid & 63;
    const int bt = wv & 3, kh = wv >> 2;
    const int hc0 = blockIdx.x * 16;
    const int l15 = lane & 15, l4 = lane >> 4;

    // stage quadrant 0,1 weight rows for this hc-slice
    for (int s = tid; s < 32 * 128; s += 512) {
        const int row = s >> 7, c8 = (s & 127) * 8;
        const int g = (row >> 4) * 1024 + hc0 + (row & 15);
        *(bf16x8*)&Bs[row][c8] = *(const bf16x8*)&Whh[(size_t)g * 1024u + c8];
    }

    const int brow = bt * 16 + l4 * 4;
    float creg[4];
    if (kh == 0) {
        if (t0 == 0) { creg[0] = creg[1] = creg[2] = creg[3] = 0.f; }
        else {
            #pragma unroll
            for (int r = 0; r < 4; ++r)
                creg[r] = cbuf[(size_t)(brow + r) * 1024u + hc0 + l15];
        }
    }
    __syncthreads();

    const int arow = bt * 16 + l15;
    const int kbase = kh * 512;
    const size_t wq2 = (size_t)(2048 + hc0 + l15) * 1024u;
    const size_t wq3 = (size_t)(3072 + hc0 + l15) * 1024u;

    for (int ts = 0; ts < nt; ++ts) {
        const int t = t0 + ts;
        const ushort* hread = hbuf + (size_t)(t & 1) * 65536u;
        f32x4 acc[4];
        #pragma unroll
        for (int q = 0; q < 4; ++q) acc[q] = (f32x4){0.f, 0.f, 0.f, 0.f};

        #pragma unroll 8
        for (int ki = 0; ki < 16; ++ki) {
            const int k = kbase + ki * 32 + l4 * 8;
            bf16x8 af = *(const bf16x8*)&hread[(size_t)arow * 1024u + k];
            bf16x8 b0 = *(const bf16x8*)&Bs[l15][k];
            bf16x8 b1 = *(const bf16x8*)&Bs[16 + l15][k];
            bf16x8 b2 = *(const bf16x8*)&Whh[wq2 + k];
            bf16x8 b3 = *(const bf16x8*)&Whh[wq3 + k];
            acc[0] = __builtin_amdgcn_mfma_f32_16x16x32_bf16(af, b0, acc[0], 0, 0, 0);
            acc[1] = __builtin_amdgcn_mfma_f32_16x16x32_bf16(af, b1, acc[1], 0, 0, 0);
            acc[2] = __builtin_amdgcn_mfma_f32_16x16x32_bf16(af, b2, acc[2], 0, 0, 0);
            acc[3] = __builtin_amdgcn_mfma_f32_16x16x32_bf16(af, b3, acc[3], 0, 0, 0);
        }

        if (kh == 1) {
            #pragma unroll
            for (int q = 0; q < 4; ++q)
                *(f32x4*)&red[bt][lane][q * 4] = acc[q];
        }
        __syncthreads();
        if (kh == 0) {
            #pragma unroll
            for (int q = 0; q < 4; ++q) {
                const f32x4 p = *(const f32x4*)&red[bt][lane][q * 4];
                acc[q].x += p.x; acc[q].y += p.y; acc[q].z += p.z; acc[q].w += p.w;
            }
            ushort* hw = hbuf + (size_t)((t + 1) & 1) * 65536u;
            #pragma unroll
            for (int r = 0; r < 4; ++r) {
                const int b = brow + r;
                const size_t xb = (size_t)(ts * 64 + b) * 4096u + hc0 + l15;
                const float s0 = acc[0][r] + b2f(xp[xb]);
                const float s1 = acc[1][r] + b2f(xp[xb + 1024]);
                const float s2 = acc[2][r] + b2f(xp[xb + 2048]);
                const float s3 = acc[3][r] + b2f(xp[xb + 3072]);
                const float ig = sigm(s0), fg = sigm(s1);
                const float gg = tanhf(s2), og = sigm(s3);
                const float c = fg * creg[r] + ig * gg;
                const float h = og * tanhf(c);
                creg[r] = c;
                const ushort hb = f2b(h);
                hw[(size_t)b * 1024u + hc0 + l15] = hb;
                if (ys) ys[(size_t)(t * 64 + b) * 1024u + hc0 + l15] = hb;
                if (t == 255) {
                    outHC[(size_t)layer * 65536u + (size_t)b * 1024u + hc0 + l15] = h;
                    outHC[131072u + (size_t)layer * 65536u + (size_t)b * 1024u + hc0 + l15] = c;
                }
            }
        }
        // grid barrier (sense-reversal, device scope)
        __syncthreads();
        if (tid == 0) {
            __threadfence();
            const unsigned g = __hip_atomic_load(&bar[1], __ATOMIC_RELAXED, __HIP_MEMORY_SCOPE_AGENT);
            if (atomicAdd(&bar[0], 1u) == 63u) {
                __hip_atomic_store(&bar[0], 0u, __ATOMIC_RELAXED, __HIP_MEMORY_SCOPE_AGENT);
                __threadfence();
                atomicAdd(&bar[1], 1u);
            } else {
                while (__hip_atomic_load(&bar[1], __ATOMIC_RELAXED, __HIP_MEMORY_SCOPE_AGENT) == g)
                    __builtin_amdgcn_s_sleep(1);
                __threadfence();
            }
        }
        __syncthreads();
    }

    if (kh == 0) {
        #pragma unroll
        for (int r = 0; r < 4; ++r)
            cbuf[(size_t)(brow + r) * 1024u + hc0 + l15] = creg[r];
    }
}

// ---------------------------------------------------------------------------
extern "C" void kernel_launch(void* const* d_in, const int* in_sizes, int n_in,
                              void* d_out, int out_size, void* d_ws, size_t ws_size,
                              hipStream_t stream) {
    (void)in_sizes; (void)n_in; (void)out_size; (void)ws_size;
    const int*   idx  = (const int*)d_in[0];
    const float* emb  = (const float*)d_in[1];
    const float* wih[2] = {(const float*)d_in[2], (const float*)d_in[6]};
    const float* whh[2] = {(const float*)d_in[3], (const float*)d_in[7]};
    const float* bih[2] = {(const float*)d_in[4], (const float*)d_in[8]};
    const float* bhh[2] = {(const float*)d_in[5], (const float*)d_in[9]};
    float* out = (float*)d_out;

    // ws layout (bytes)
    char* p = (char*)d_ws;
    ushort* xg    = (ushort*)p;  p += 33554432;   // 16384x1024 bf16
    ushort* ys0   = (ushort*)p;  p += 33554432;   // 16384x1024 bf16
    ushort* wihb0 = (ushort*)p;  p += 8388608;    // 4096x1024 bf16
    ushort* whhb0 = (ushort*)p;  p += 8388608;
    ushort* wihb1 = (ushort*)p;  p += 8388608;
    ushort* whhb1 = (ushort*)p;  p += 8388608;
    ushort* xp    = (ushort*)p;  p += 33554432;   // 4096x4096 bf16 chunk
    ushort* hbuf  = (ushort*)p;  p += 262144;     // 2x64x1024 bf16
    float*  cbuf  = (float*)p;   p += 262144;     // 64x1024 f32
    float*  bsum0 = (float*)p;   p += 16384;
    float*  bsum1 = (float*)p;   p += 16384;
    unsigned* bar = (unsigned*)p;

    hipMemsetAsync(bar, 0, 256, stream);
    prep_weights<<<4096, 256, 0, stream>>>(
        wih[0], whh[0], bih[0], bhh[0], wih[1], whh[1], bih[1], bhh[1],
        wihb0, whhb0, wihb1, whhb1, bsum0, bsum1);
    gather_x<<<16384, 256, 0, stream>>>(idx, emb, xg);

    const ushort* wihbL[2] = {wihb0, wihb1};
    const ushort* whhbL[2] = {whhb0, whhb1};
    const float*  bsumL[2] = {bsum0, bsum1};

    for (int L = 0; L < 2; ++L) {
        hipMemsetAsync(hbuf, 0, 262144, stream);
        const ushort* Abase = (L == 0) ? xg : ys0;
        ushort* ysout = (L == 0) ? ys0 : nullptr;
        for (int ch = 0; ch < 4; ++ch) {
            inproj_mfma<<<dim3(32, 32), 256, 0, stream>>>(
                Abase, wihbL[L], bsumL[L], xp, ch * 4096);
            lstm_persist<<<64, 512, 0, stream>>>(
                whhbL[L], xp, hbuf, cbuf, ysout, out, bar, ch * 64, 64, L);
        }
    }
}

// Round 3
// 10513.112 us; speedup vs baseline: 1.2218x; 1.0408x over previous
//
#include <hip/hip_runtime.h>
#include <hip/hip_bf16.h>

typedef __attribute__((ext_vector_type(8))) short bf16x8;
typedef __attribute__((ext_vector_type(4))) float f32x4;

__device__ __forceinline__ ushort f2b(float f) {
    union { float f; unsigned u; } v; v.f = f;
    unsigned r = v.u + 0x7FFFu + ((v.u >> 16) & 1u);
    return (ushort)(r >> 16);
}
__device__ __forceinline__ float b2f(ushort u) {
    union { unsigned u; float f; } v; v.u = ((unsigned)u) << 16;
    return v.f;
}
__device__ __forceinline__ float sigm(float x) {
    return 1.f / (1.f + __expf(-x));
}

// ---------------------------------------------------------------------------
// prep_weights: f32 -> bf16 weight conversion + bias sum (b_ih + b_hh).
// ---------------------------------------------------------------------------
__global__ __launch_bounds__(256) void prep_weights(
    const float* __restrict__ wih0, const float* __restrict__ whh0,
    const float* __restrict__ bih0, const float* __restrict__ bhh0,
    const float* __restrict__ wih1, const float* __restrict__ whh1,
    const float* __restrict__ bih1, const float* __restrict__ bhh1,
    ushort* __restrict__ wih0b, ushort* __restrict__ whh0b,
    ushort* __restrict__ wih1b, ushort* __restrict__ whh1b,
    float* __restrict__ bsum0, float* __restrict__ bsum1)
{
    const int i = blockIdx.x * 256 + threadIdx.x;
    const int e = i * 4;
    float4 v;
    v = *(const float4*)&wih0[e];
    *(ushort4*)&wih0b[e] = make_ushort4(f2b(v.x), f2b(v.y), f2b(v.z), f2b(v.w));
    v = *(const float4*)&whh0[e];
    *(ushort4*)&whh0b[e] = make_ushort4(f2b(v.x), f2b(v.y), f2b(v.z), f2b(v.w));
    v = *(const float4*)&wih1[e];
    *(ushort4*)&wih1b[e] = make_ushort4(f2b(v.x), f2b(v.y), f2b(v.z), f2b(v.w));
    v = *(const float4*)&whh1[e];
    *(ushort4*)&whh1b[e] = make_ushort4(f2b(v.x), f2b(v.y), f2b(v.z), f2b(v.w));
    if (i < 1024) {
        const int b4 = i * 4;
        float4 a0 = *(const float4*)&bih0[b4];
        float4 b0 = *(const float4*)&bhh0[b4];
        *(float4*)&bsum0[b4] = make_float4(a0.x + b0.x, a0.y + b0.y, a0.z + b0.z, a0.w + b0.w);
        float4 a1 = *(const float4*)&bih1[b4];
        float4 b1 = *(const float4*)&bhh1[b4];
        *(float4*)&bsum1[b4] = make_float4(a1.x + b1.x, a1.y + b1.y, a1.z + b1.z, a1.w + b1.w);
    }
}

// ---------------------------------------------------------------------------
// gather_x: xg[row][:] = bf16(emb[idx[row]][:]); row = t*64+b, 16384 rows.
// ---------------------------------------------------------------------------
__global__ __launch_bounds__(256) void gather_x(
    const int* __restrict__ idx, const float* __restrict__ emb,
    ushort* __restrict__ xg)
{
    const int row = blockIdx.x;
    const int c = threadIdx.x;
    const int v = idx[row];
    const float4 f = *(const float4*)&emb[(size_t)v * 1024u + c * 4];
    *(ushort4*)&xg[(size_t)row * 1024u + c * 4] =
        make_ushort4(f2b(f.x), f2b(f.y), f2b(f.z), f2b(f.w));
}

// ---------------------------------------------------------------------------
// inproj_mfma: xpT[g][m] = sum_k A[mbase+m][k]*W[g][k] + bsum[g]  (bf16 out,
// TRANSPOSED so the persistent kernel reads batch-contiguous columns).
// 128x128 tile, 4 waves x 64x64, 16x16x32 bf16 MFMA.
// ---------------------------------------------------------------------------
__global__ __launch_bounds__(256) void inproj_mfma(
    const ushort* __restrict__ A, const ushort* __restrict__ W,
    const float* __restrict__ bsum, ushort* __restrict__ xpT, int mbase)
{
    __shared__ ushort As[128][72];
    __shared__ ushort Bsh[128][72];
    const int tid = threadIdx.x;
    const int wv = tid >> 6, lane = tid & 63;
    const int l15 = lane & 15, l4 = lane >> 4;
    const int m0 = blockIdx.y * 128, n0 = blockIdx.x * 128;
    const int wm = (wv & 1) * 64, wn = (wv >> 1) * 64;

    f32x4 acc[4][4];
    #pragma unroll
    for (int i = 0; i < 4; ++i)
        #pragma unroll
        for (int j = 0; j < 4; ++j) acc[i][j] = (f32x4){0.f, 0.f, 0.f, 0.f};

    for (int k0 = 0; k0 < 1024; k0 += 64) {
        __syncthreads();
        #pragma unroll
        for (int s4 = 0; s4 < 4; ++s4) {
            const int s = tid + s4 * 256;
            const int row = s >> 3, c8 = (s & 7) * 8;
            *(bf16x8*)&As[row][c8] =
                *(const bf16x8*)&A[(size_t)(mbase + m0 + row) * 1024u + k0 + c8];
            *(bf16x8*)&Bsh[row][c8] =
                *(const bf16x8*)&W[(size_t)(n0 + row) * 1024u + k0 + c8];
        }
        __syncthreads();
        #pragma unroll
        for (int kk = 0; kk < 2; ++kk) {
            bf16x8 af[4], bfr[4];
            #pragma unroll
            for (int i = 0; i < 4; ++i) {
                af[i]  = *(const bf16x8*)&As[wm + i * 16 + l15][kk * 32 + l4 * 8];
                bfr[i] = *(const bf16x8*)&Bsh[wn + i * 16 + l15][kk * 32 + l4 * 8];
            }
            #pragma unroll
            for (int i = 0; i < 4; ++i)
                #pragma unroll
                for (int j = 0; j < 4; ++j)
                    acc[i][j] = __builtin_amdgcn_mfma_f32_16x16x32_bf16(
                        af[i], bfr[j], acc[i][j], 0, 0, 0);
        }
    }
    #pragma unroll
    for (int i = 0; i < 4; ++i) {
        const int m = m0 + wm + i * 16 + l4 * 4;   // chunk-local col, 4-aligned
        #pragma unroll
        for (int j = 0; j < 4; ++j) {
            const int g = n0 + wn + j * 16 + l15;
            const float bs = bsum[g];
            ushort4 o = make_ushort4(f2b(acc[i][j][0] + bs), f2b(acc[i][j][1] + bs),
                                     f2b(acc[i][j][2] + bs), f2b(acc[i][j][3] + bs));
            *(ushort4*)&xpT[(size_t)g * 4096u + m] = o;
        }
    }
}

// ---------------------------------------------------------------------------
// lstm_persist: 64 timesteps, 128 blocks x 256 thr (4 waves).
// Block owns hc slice [bid*8, bid*8+8): 32 gate rows (hcl*4+q order), all
// weights in LDS. Wave w = K-slice [256w,256w+256): M=64, N=32 MFMA, then
// cross-wave LDS reduce by m-tile, wave-local pointwise, c in registers.
// Grid sync: per-block monotonic flag + 2-flag/lane poll by wave 0.
// ---------------------------------------------------------------------------
__global__ __launch_bounds__(256) void lstm_persist(
    const ushort* __restrict__ Whh,   // bf16 [4096][1024]
    const ushort* __restrict__ xpT,   // bf16 [4096][4096] chunk, col=ts*64+b
    ushort* __restrict__ hbuf,        // bf16 [2][64][1024] ping-pong
    float* __restrict__ cbuf,         // f32 [64][1024]
    ushort* __restrict__ ys,          // bf16 [16384][1024] or null
    float* __restrict__ outHC,        // h0,h1,c0,c1 each 64x1024 f32
    unsigned* __restrict__ flags,     // [128] monotonic step flags
    int t0, int nt, int layer)
{
    __shared__ ushort Ws[32][1032];           // 66 KB, row = hcl*4+q
    __shared__ float red[4][4][2][64][4];     // 32 KB [mtile][src][j][lane][r]
    __shared__ float gs[4][16][33];           // 8.4 KB per-wave gate sums

    const int tid = threadIdx.x;
    const int wv = tid >> 6, lane = tid & 63;
    const int l15 = lane & 15, l4 = lane >> 4;
    const int bid = blockIdx.x;
    const int hc0 = bid * 8;

    // stage weights: LDS row = hcl*4+q  <->  g = q*1024 + hc0 + hcl
    for (int s = tid; s < 32 * 128; s += 256) {
        const int row = s >> 7, c8 = (s & 127) * 8;
        const int g = (row & 3) * 1024 + hc0 + (row >> 2);
        *(bf16x8*)&Ws[row][c8] = *(const bf16x8*)&Whh[(size_t)g * 1024u + c8];
    }

    // pointwise ownership: slot s: b = wv*16 + (lane>>3) + 8s, hc = hc0 + (lane&7)
    const int pb0 = wv * 16 + (lane >> 3);
    const int phc = lane & 7;
    float cs[2];
    if (t0 == 0) { cs[0] = cs[1] = 0.f; }
    else {
        cs[0] = cbuf[(size_t)pb0 * 1024u + hc0 + phc];
        cs[1] = cbuf[(size_t)(pb0 + 8) * 1024u + hc0 + phc];
    }
    __syncthreads();

    const int kbase = wv * 256;
    unsigned tgt = (unsigned)(layer * 256 + t0);

    for (int ts = 0; ts < nt; ++ts) {
        const int t = t0 + ts;
        const ushort* hr = hbuf + (size_t)(t & 1) * 65536u;

        // xp prefetch (latency hidden under MFMA phase)
        ushort xpv[2][4];
        #pragma unroll
        for (int s = 0; s < 2; ++s)
            #pragma unroll
            for (int q = 0; q < 4; ++q)
                xpv[s][q] = xpT[(size_t)(q * 1024 + hc0 + phc) * 4096u
                                + ts * 64 + pb0 + 8 * s];

        f32x4 acc[4][2];
        #pragma unroll
        for (int i = 0; i < 4; ++i) {
            acc[i][0] = (f32x4){0.f, 0.f, 0.f, 0.f};
            acc[i][1] = (f32x4){0.f, 0.f, 0.f, 0.f};
        }
        #pragma unroll
        for (int kk = 0; kk < 8; ++kk) {
            const int k = kbase + kk * 32 + l4 * 8;
            bf16x8 bf0 = *(const bf16x8*)&Ws[l15][k];
            bf16x8 bf1 = *(const bf16x8*)&Ws[16 + l15][k];
            #pragma unroll
            for (int i = 0; i < 4; ++i) {
                bf16x8 af = *(const bf16x8*)&hr[(size_t)(i * 16 + l15) * 1024u + k];
                acc[i][0] = __builtin_amdgcn_mfma_f32_16x16x32_bf16(af, bf0, acc[i][0], 0, 0, 0);
                acc[i][1] = __builtin_amdgcn_mfma_f32_16x16x32_bf16(af, bf1, acc[i][1], 0, 0, 0);
            }
        }

        // cross-wave K reduce: wave w keeps m-tile w
        #pragma unroll
        for (int i = 0; i < 4; ++i) {
            if (i != wv) {
                *(f32x4*)&red[i][wv][0][lane][0] = acc[i][0];
                *(f32x4*)&red[i][wv][1][lane][0] = acc[i][1];
            }
        }
        __syncthreads();
        f32x4 fin0 = (f32x4){0.f,0.f,0.f,0.f}, fin1 = (f32x4){0.f,0.f,0.f,0.f};
        #pragma unroll
        for (int i = 0; i < 4; ++i) {
            if (i == wv) { fin0 = acc[i][0]; fin1 = acc[i][1]; }
        }
        #pragma unroll
        for (int src = 0; src < 4; ++src) {
            if (src != wv) {
                const f32x4 r0 = *(const f32x4*)&red[wv][src][0][lane][0];
                const f32x4 r1 = *(const f32x4*)&red[wv][src][1][lane][0];
                fin0 += r0; fin1 += r1;
            }
        }

        // wave-local gsum bounce (padded 33 -> no 16-way conflicts)
        #pragma unroll
        for (int r = 0; r < 4; ++r) {
            gs[wv][l4 * 4 + r][l15]      = fin0[r];
            gs[wv][l4 * 4 + r][16 + l15] = fin1[r];
        }
        // pointwise (wave-local; lgkmcnt ordering within wave)
        ushort* hw = hbuf + (size_t)((t + 1) & 1) * 65536u;
        #pragma unroll
        for (int s = 0; s < 2; ++s) {
            const int bloc = (lane >> 3) + 8 * s;
            const int b = wv * 16 + bloc;
            const float g0 = gs[wv][bloc][phc * 4 + 0] + b2f(xpv[s][0]);
            const float g1 = gs[wv][bloc][phc * 4 + 1] + b2f(xpv[s][1]);
            const float g2 = gs[wv][bloc][phc * 4 + 2] + b2f(xpv[s][2]);
            const float g3 = gs[wv][bloc][phc * 4 + 3] + b2f(xpv[s][3]);
            const float ig = sigm(g0), fg = sigm(g1);
            const float gg = tanhf(g2), og = sigm(g3);
            const float c = fg * cs[s] + ig * gg;
            const float h = og * tanhf(c);
            cs[s] = c;
            const ushort hb = f2b(h);
            hw[(size_t)b * 1024u + hc0 + phc] = hb;
            if (ys) ys[(size_t)(t * 64 + b) * 1024u + hc0 + phc] = hb;
            if (t == 255) {
                outHC[(size_t)layer * 65536u + (size_t)b * 1024u + hc0 + phc] = h;
                outHC[131072u + (size_t)layer * 65536u + (size_t)b * 1024u + hc0 + phc] = c;
            }
        }

        // release h, signal, poll all 128 flags, acquire
        __builtin_amdgcn_fence(__ATOMIC_RELEASE, "agent");
        __syncthreads();
        ++tgt;
        if (tid == 0)
            __hip_atomic_store(&flags[bid], tgt, __ATOMIC_RELAXED, __HIP_MEMORY_SCOPE_AGENT);
        if (wv == 0) {
            for (;;) {
                const unsigned f0 = __hip_atomic_load(&flags[lane], __ATOMIC_RELAXED, __HIP_MEMORY_SCOPE_AGENT);
                const unsigned f1 = __hip_atomic_load(&flags[lane + 64], __ATOMIC_RELAXED, __HIP_MEMORY_SCOPE_AGENT);
                if (__all(f0 >= tgt && f1 >= tgt)) break;
                __builtin_amdgcn_s_sleep(1);
            }
        }
        __syncthreads();
        __builtin_amdgcn_fence(__ATOMIC_ACQUIRE, "agent");
    }

    cbuf[(size_t)pb0 * 1024u + hc0 + phc] = cs[0];
    cbuf[(size_t)(pb0 + 8) * 1024u + hc0 + phc] = cs[1];
}

// ---------------------------------------------------------------------------
extern "C" void kernel_launch(void* const* d_in, const int* in_sizes, int n_in,
                              void* d_out, int out_size, void* d_ws, size_t ws_size,
                              hipStream_t stream) {
    (void)in_sizes; (void)n_in; (void)out_size; (void)ws_size;
    const int*   idx  = (const int*)d_in[0];
    const float* emb  = (const float*)d_in[1];
    const float* wih[2] = {(const float*)d_in[2], (const float*)d_in[6]};
    const float* whh[2] = {(const float*)d_in[3], (const float*)d_in[7]};
    const float* bih[2] = {(const float*)d_in[4], (const float*)d_in[8]};
    const float* bhh[2] = {(const float*)d_in[5], (const float*)d_in[9]};
    float* out = (float*)d_out;

    char* p = (char*)d_ws;
    ushort* xg    = (ushort*)p;  p += 33554432;   // 16384x1024 bf16
    ushort* ys0   = (ushort*)p;  p += 33554432;   // 16384x1024 bf16
    ushort* wihb0 = (ushort*)p;  p += 8388608;
    ushort* whhb0 = (ushort*)p;  p += 8388608;
    ushort* wihb1 = (ushort*)p;  p += 8388608;
    ushort* whhb1 = (ushort*)p;  p += 8388608;
    ushort* xpT   = (ushort*)p;  p += 33554432;   // [4096 g][4096 m] bf16 chunk
    ushort* hbuf  = (ushort*)p;  p += 262144;     // 2x64x1024 bf16
    float*  cbuf  = (float*)p;   p += 262144;     // 64x1024 f32
    float*  bsum0 = (float*)p;   p += 16384;
    float*  bsum1 = (float*)p;   p += 16384;
    unsigned* flags = (unsigned*)p;               // 128 x u32

    hipMemsetAsync(flags, 0, 512, stream);
    prep_weights<<<4096, 256, 0, stream>>>(
        wih[0], whh[0], bih[0], bhh[0], wih[1], whh[1], bih[1], bhh[1],
        wihb0, whhb0, wihb1, whhb1, bsum0, bsum1);
    gather_x<<<16384, 256, 0, stream>>>(idx, emb, xg);

    const ushort* wihbL[2] = {wihb0, wihb1};
    const ushort* whhbL[2] = {whhb0, whhb1};
    const float*  bsumL[2] = {bsum0, bsum1};

    for (int L = 0; L < 2; ++L) {
        hipMemsetAsync(hbuf, 0, 262144, stream);
        const ushort* Abase = (L == 0) ? xg : ys0;
        ushort* ysout = (L == 0) ? ys0 : nullptr;
        for (int ch = 0; ch < 4; ++ch) {
            inproj_mfma<<<dim3(32, 32), 256, 0, stream>>>(
                Abase, wihbL[L], bsumL[L], xpT, ch * 4096);
            lstm_persist<<<128, 256, 0, stream>>>(
                whhbL[L], xpT, hbuf, cbuf, ysout, out, flags, ch * 64, 64, L);
        }
    }
}

// Round 4
// 5654.615 us; speedup vs baseline: 2.2716x; 1.8592x over previous
//
#include <hip/hip_runtime.h>
#include <hip/hip_bf16.h>

typedef __attribute__((ext_vector_type(8))) short bf16x8;
typedef __attribute__((ext_vector_type(4))) float f32x4;

__device__ __forceinline__ ushort f2b(float f) {
    union { float f; unsigned u; } v; v.f = f;
    unsigned r = v.u + 0x7FFFu + ((v.u >> 16) & 1u);
    return (ushort)(r >> 16);
}
__device__ __forceinline__ float b2f(ushort u) {
    union { unsigned u; float f; } v; v.u = ((unsigned)u) << 16;
    return v.f;
}
__device__ __forceinline__ float sigm(float x) {
    return 1.f / (1.f + __expf(-x));
}

// Coherent (L2-bypass, device-visible) load/store — no cache-maintenance ops.
#define HLOAD(dst, p, off) \
    asm volatile("global_load_dwordx4 %0, %1, off offset:" #off " sc0 sc1" \
                 : "=v"(dst) : "v"(p))
#define HSTORE(p, v) \
    asm volatile("global_store_dword %0, %1, off sc0 sc1" \
                 :: "v"(p), "v"(v) : "memory")

// ---------------------------------------------------------------------------
// prep_weights: f32 -> bf16 weight conversion + bias sum (b_ih + b_hh).
// ---------------------------------------------------------------------------
__global__ __launch_bounds__(256) void prep_weights(
    const float* __restrict__ wih0, const float* __restrict__ whh0,
    const float* __restrict__ bih0, const float* __restrict__ bhh0,
    const float* __restrict__ wih1, const float* __restrict__ whh1,
    const float* __restrict__ bih1, const float* __restrict__ bhh1,
    ushort* __restrict__ wih0b, ushort* __restrict__ whh0b,
    ushort* __restrict__ wih1b, ushort* __restrict__ whh1b,
    float* __restrict__ bsum0, float* __restrict__ bsum1)
{
    const int i = blockIdx.x * 256 + threadIdx.x;
    const int e = i * 4;
    float4 v;
    v = *(const float4*)&wih0[e];
    *(ushort4*)&wih0b[e] = make_ushort4(f2b(v.x), f2b(v.y), f2b(v.z), f2b(v.w));
    v = *(const float4*)&whh0[e];
    *(ushort4*)&whh0b[e] = make_ushort4(f2b(v.x), f2b(v.y), f2b(v.z), f2b(v.w));
    v = *(const float4*)&wih1[e];
    *(ushort4*)&wih1b[e] = make_ushort4(f2b(v.x), f2b(v.y), f2b(v.z), f2b(v.w));
    v = *(const float4*)&whh1[e];
    *(ushort4*)&whh1b[e] = make_ushort4(f2b(v.x), f2b(v.y), f2b(v.z), f2b(v.w));
    if (i < 1024) {
        const int b4 = i * 4;
        float4 a0 = *(const float4*)&bih0[b4];
        float4 b0 = *(const float4*)&bhh0[b4];
        *(float4*)&bsum0[b4] = make_float4(a0.x + b0.x, a0.y + b0.y, a0.z + b0.z, a0.w + b0.w);
        float4 a1 = *(const float4*)&bih1[b4];
        float4 b1 = *(const float4*)&bhh1[b4];
        *(float4*)&bsum1[b4] = make_float4(a1.x + b1.x, a1.y + b1.y, a1.z + b1.z, a1.w + b1.w);
    }
}

// ---------------------------------------------------------------------------
// gather_x: xg[row][:] = bf16(emb[idx[row]][:]); row = t*64+b, 16384 rows.
// ---------------------------------------------------------------------------
__global__ __launch_bounds__(256) void gather_x(
    const int* __restrict__ idx, const float* __restrict__ emb,
    ushort* __restrict__ xg)
{
    const int row = blockIdx.x;
    const int c = threadIdx.x;
    const int v = idx[row];
    const float4 f = *(const float4*)&emb[(size_t)v * 1024u + c * 4];
    *(ushort4*)&xg[(size_t)row * 1024u + c * 4] =
        make_ushort4(f2b(f.x), f2b(f.y), f2b(f.z), f2b(f.w));
}

// ---------------------------------------------------------------------------
// inproj_mfma: xp[m][g] = sum_k A[mbase+m][k]*W[g][k] + bsum[g]  (bf16 out)
// 128x128 tile, 4 waves x 64x64, 16x16x32 bf16 MFMA.
// ---------------------------------------------------------------------------
__global__ __launch_bounds__(256) void inproj_mfma(
    const ushort* __restrict__ A, const ushort* __restrict__ W,
    const float* __restrict__ bsum, ushort* __restrict__ xpout, int mbase)
{
    __shared__ ushort As[128][72];
    __shared__ ushort Bsh[128][72];
    const int tid = threadIdx.x;
    const int wv = tid >> 6, lane = tid & 63;
    const int l15 = lane & 15, l4 = lane >> 4;
    const int m0 = blockIdx.y * 128, n0 = blockIdx.x * 128;
    const int wm = (wv & 1) * 64, wn = (wv >> 1) * 64;

    f32x4 acc[4][4];
    #pragma unroll
    for (int i = 0; i < 4; ++i)
        #pragma unroll
        for (int j = 0; j < 4; ++j) acc[i][j] = (f32x4){0.f, 0.f, 0.f, 0.f};

    for (int k0 = 0; k0 < 1024; k0 += 64) {
        __syncthreads();
        #pragma unroll
        for (int s4 = 0; s4 < 4; ++s4) {
            const int s = tid + s4 * 256;
            const int row = s >> 3, c8 = (s & 7) * 8;
            *(bf16x8*)&As[row][c8] =
                *(const bf16x8*)&A[(size_t)(mbase + m0 + row) * 1024u + k0 + c8];
            *(bf16x8*)&Bsh[row][c8] =
                *(const bf16x8*)&W[(size_t)(n0 + row) * 1024u + k0 + c8];
        }
        __syncthreads();
        #pragma unroll
        for (int kk = 0; kk < 2; ++kk) {
            bf16x8 af[4], bfr[4];
            #pragma unroll
            for (int i = 0; i < 4; ++i) {
                af[i]  = *(const bf16x8*)&As[wm + i * 16 + l15][kk * 32 + l4 * 8];
                bfr[i] = *(const bf16x8*)&Bsh[wn + i * 16 + l15][kk * 32 + l4 * 8];
            }
            #pragma unroll
            for (int i = 0; i < 4; ++i)
                #pragma unroll
                for (int j = 0; j < 4; ++j)
                    acc[i][j] = __builtin_amdgcn_mfma_f32_16x16x32_bf16(
                        af[i], bfr[j], acc[i][j], 0, 0, 0);
        }
    }
    #pragma unroll
    for (int i = 0; i < 4; ++i) {
        const int m = m0 + wm + i * 16 + l4 * 4;
        #pragma unroll
        for (int j = 0; j < 4; ++j) {
            const int g = n0 + wn + j * 16 + l15;
            const float bs = bsum[g];
            #pragma unroll
            for (int r = 0; r < 4; ++r)
                xpout[(size_t)(m + r) * 4096u + g] = f2b(acc[i][j][r] + bs);
        }
    }
}

// ---------------------------------------------------------------------------
// lstm_persist: 64 timesteps, 128 blocks x 256 thr (4 waves).
// Block owns hc slice [bid*8, bid*8+8): 32 gate rows, weights in LDS.
// Wave wv = K-slice [256wv, 256wv+256): M=64, N=32 MFMA; h fragments are
// prefetched with coherent (sc0 sc1) asm loads into 32 regs; cross-wave
// K-reduce in LDS; pointwise wave-local; h written with coherent packed
// uint stores. NO agent fences anywhere — ordering is vmcnt drain + flag.
// ---------------------------------------------------------------------------
__global__ __launch_bounds__(256) void lstm_persist(
    const ushort* __restrict__ Whh,   // bf16 [4096][1024]
    const ushort* __restrict__ xp,    // bf16 [4096 m][4096 g] chunk rows
    ushort* __restrict__ hbuf,        // bf16 [2][64][1024] ping-pong
    float* __restrict__ cbuf,         // f32 [64][1024]
    ushort* __restrict__ ys,          // bf16 [16384][1024] or null
    float* __restrict__ outHC,        // h0,h1,c0,c1 each 64x1024 f32
    unsigned* __restrict__ flags,     // [128] monotonic step flags
    int t0, int nt, int layer)
{
    __shared__ ushort Ws[32][1032];           // 66 KB, row = hcl*4+q
    __shared__ float red[4][4][2][64][4];     // 32 KB
    __shared__ float gs[4][16][33];           // 8.4 KB

    const int tid = threadIdx.x;
    const int wv = tid >> 6, lane = tid & 63;
    const int l15 = lane & 15, l4 = lane >> 4;
    const int bid = blockIdx.x;
    const int hc0 = bid * 8;

    // stage weights: LDS row = hcl*4+q  <->  g = q*1024 + hc0 + hcl
    for (int s = tid; s < 32 * 128; s += 256) {
        const int row = s >> 7, c8 = (s & 127) * 8;
        const int g = (row & 3) * 1024 + hc0 + (row >> 2);
        *(bf16x8*)&Ws[row][c8] = *(const bf16x8*)&Whh[(size_t)g * 1024u + c8];
    }

    // pointwise ownership: pb = wv*16 + (lane>>2), hc pair pp = lane&3
    const int pb = wv * 16 + (lane >> 2);
    const int pp = lane & 3;
    float cs[2];
    if (t0 == 0) { cs[0] = cs[1] = 0.f; }
    else {
        float2 c2 = *(const float2*)&cbuf[(size_t)pb * 1024u + hc0 + 2 * pp];
        cs[0] = c2.x; cs[1] = c2.y;
    }
    __syncthreads();

    const int kbase = wv * 256;
    const unsigned* xpu = (const unsigned*)xp;
    unsigned tgt = (unsigned)(layer * 256 + t0);

    for (int ts = 0; ts < nt; ++ts) {
        const int t = t0 + ts;
        const ushort* hr = hbuf + (size_t)(t & 1) * 65536u;

        // xp prefetch: 4 uint (hc-pair per gate), normal cached loads
        unsigned xq[4];
        #pragma unroll
        for (int q = 0; q < 4; ++q)
            xq[q] = xpu[(size_t)(ts * 64 + pb) * 2048u + q * 512 + (hc0 >> 1) + pp];

        // coherent h prefetch: 32 fragments (full M=64 x K=256 wave slice)
        bf16x8 hf[8][4];
        const ushort* rb[4];
        #pragma unroll
        for (int i = 0; i < 4; ++i)
            rb[i] = hr + (size_t)(i * 16 + l15) * 1024u + kbase + l4 * 8;
        #pragma unroll
        for (int i = 0; i < 4; ++i) {
            HLOAD(hf[0][i], rb[i], 0);
            HLOAD(hf[1][i], rb[i], 64);
            HLOAD(hf[2][i], rb[i], 128);
            HLOAD(hf[3][i], rb[i], 192);
            HLOAD(hf[4][i], rb[i], 256);
            HLOAD(hf[5][i], rb[i], 320);
            HLOAD(hf[6][i], rb[i], 384);
            HLOAD(hf[7][i], rb[i], 448);
        }
        asm volatile("s_waitcnt vmcnt(0)" ::: "memory");
        __builtin_amdgcn_sched_barrier(0);   // keep MFMAs below the wait

        f32x4 acc[4][2];
        #pragma unroll
        for (int i = 0; i < 4; ++i) {
            acc[i][0] = (f32x4){0.f, 0.f, 0.f, 0.f};
            acc[i][1] = (f32x4){0.f, 0.f, 0.f, 0.f};
        }
        #pragma unroll
        for (int kk = 0; kk < 8; ++kk) {
            const int k = kbase + kk * 32 + l4 * 8;
            bf16x8 bf0 = *(const bf16x8*)&Ws[l15][k];
            bf16x8 bf1 = *(const bf16x8*)&Ws[16 + l15][k];
            #pragma unroll
            for (int i = 0; i < 4; ++i) {
                acc[i][0] = __builtin_amdgcn_mfma_f32_16x16x32_bf16(hf[kk][i], bf0, acc[i][0], 0, 0, 0);
                acc[i][1] = __builtin_amdgcn_mfma_f32_16x16x32_bf16(hf[kk][i], bf1, acc[i][1], 0, 0, 0);
            }
        }

        // cross-wave K reduce: wave wv keeps m-tile wv
        #pragma unroll
        for (int i = 0; i < 4; ++i) {
            if (i != wv) {
                *(f32x4*)&red[i][wv][0][lane][0] = acc[i][0];
                *(f32x4*)&red[i][wv][1][lane][0] = acc[i][1];
            }
        }
        __syncthreads();
        f32x4 fin0 = (f32x4){0.f,0.f,0.f,0.f}, fin1 = (f32x4){0.f,0.f,0.f,0.f};
        #pragma unroll
        for (int i = 0; i < 4; ++i)
            if (i == wv) { fin0 = acc[i][0]; fin1 = acc[i][1]; }
        #pragma unroll
        for (int src = 0; src < 4; ++src) {
            if (src != wv) {
                fin0 += *(const f32x4*)&red[wv][src][0][lane][0];
                fin1 += *(const f32x4*)&red[wv][src][1][lane][0];
            }
        }

        // wave-local gate-sum bounce: gs[wv][m_loc][gate_row]
        #pragma unroll
        for (int r = 0; r < 4; ++r) {
            gs[wv][l4 * 4 + r][l15]      = fin0[r];
            gs[wv][l4 * 4 + r][16 + l15] = fin1[r];
        }

        // pointwise: thread owns (pb, hc = hc0 + 2*pp + {0,1})
        ushort* hw = hbuf + (size_t)((t + 1) & 1) * 65536u;
        float hv[2];
        #pragma unroll
        for (int d = 0; d < 2; ++d) {
            const int grow = (2 * pp + d) * 4;
            const float g0 = gs[wv][lane >> 2][grow + 0] + b2f((ushort)(d ? (xq[0] >> 16) : (xq[0] & 0xffff)));
            const float g1 = gs[wv][lane >> 2][grow + 1] + b2f((ushort)(d ? (xq[1] >> 16) : (xq[1] & 0xffff)));
            const float g2 = gs[wv][lane >> 2][grow + 2] + b2f((ushort)(d ? (xq[2] >> 16) : (xq[2] & 0xffff)));
            const float g3 = gs[wv][lane >> 2][grow + 3] + b2f((ushort)(d ? (xq[3] >> 16) : (xq[3] & 0xffff)));
            const float ig = sigm(g0), fg = sigm(g1);
            const float gg = tanhf(g2), og = sigm(g3);
            const float c = fg * cs[d] + ig * gg;
            hv[d] = og * tanhf(c);
            cs[d] = c;
        }
        const unsigned hpack = (unsigned)f2b(hv[0]) | ((unsigned)f2b(hv[1]) << 16);
        unsigned* hwp = (unsigned*)(hw + (size_t)pb * 1024u + hc0 + 2 * pp);
        HSTORE(hwp, hpack);
        if (ys)
            *(unsigned*)(ys + (size_t)(t * 64 + pb) * 1024u + hc0 + 2 * pp) = hpack;
        if (t == 255) {
            #pragma unroll
            for (int d = 0; d < 2; ++d) {
                const int hc = hc0 + 2 * pp + d;
                outHC[(size_t)layer * 65536u + (size_t)pb * 1024u + hc] = hv[d];
                outHC[131072u + (size_t)layer * 65536u + (size_t)pb * 1024u + hc] = cs[d];
            }
        }

        // drain this wave's stores to the coherence point, then signal
        asm volatile("s_waitcnt vmcnt(0)" ::: "memory");
        __syncthreads();
        ++tgt;
        if (tid == 0)
            __hip_atomic_store(&flags[bid], tgt, __ATOMIC_RELAXED, __HIP_MEMORY_SCOPE_AGENT);
        if (wv == 0) {
            for (;;) {
                const unsigned f0 = __hip_atomic_load(&flags[lane], __ATOMIC_RELAXED, __HIP_MEMORY_SCOPE_AGENT);
                const unsigned f1 = __hip_atomic_load(&flags[lane + 64], __ATOMIC_RELAXED, __HIP_MEMORY_SCOPE_AGENT);
                if (__all(f0 >= tgt && f1 >= tgt)) break;
                __builtin_amdgcn_s_sleep(1);
            }
        }
        __syncthreads();
    }

    *(float2*)&cbuf[(size_t)pb * 1024u + hc0 + 2 * pp] = make_float2(cs[0], cs[1]);
}

// ---------------------------------------------------------------------------
extern "C" void kernel_launch(void* const* d_in, const int* in_sizes, int n_in,
                              void* d_out, int out_size, void* d_ws, size_t ws_size,
                              hipStream_t stream) {
    (void)in_sizes; (void)n_in; (void)out_size; (void)ws_size;
    const int*   idx  = (const int*)d_in[0];
    const float* emb  = (const float*)d_in[1];
    const float* wih[2] = {(const float*)d_in[2], (const float*)d_in[6]};
    const float* whh[2] = {(const float*)d_in[3], (const float*)d_in[7]};
    const float* bih[2] = {(const float*)d_in[4], (const float*)d_in[8]};
    const float* bhh[2] = {(const float*)d_in[5], (const float*)d_in[9]};
    float* out = (float*)d_out;

    char* p = (char*)d_ws;
    ushort* xg    = (ushort*)p;  p += 33554432;   // 16384x1024 bf16
    ushort* ys0   = (ushort*)p;  p += 33554432;   // 16384x1024 bf16
    ushort* wihb0 = (ushort*)p;  p += 8388608;
    ushort* whhb0 = (ushort*)p;  p += 8388608;
    ushort* wihb1 = (ushort*)p;  p += 8388608;
    ushort* whhb1 = (ushort*)p;  p += 8388608;
    ushort* xp    = (ushort*)p;  p += 33554432;   // [4096 m][4096 g] bf16 chunk
    ushort* hbuf  = (ushort*)p;  p += 262144;     // 2x64x1024 bf16
    float*  cbuf  = (float*)p;   p += 262144;     // 64x1024 f32
    float*  bsum0 = (float*)p;   p += 16384;
    float*  bsum1 = (float*)p;   p += 16384;
    unsigned* flags = (unsigned*)p;               // 128 x u32

    hipMemsetAsync(flags, 0, 512, stream);
    prep_weights<<<4096, 256, 0, stream>>>(
        wih[0], whh[0], bih[0], bhh[0], wih[1], whh[1], bih[1], bhh[1],
        wihb0, whhb0, wihb1, whhb1, bsum0, bsum1);
    gather_x<<<16384, 256, 0, stream>>>(idx, emb, xg);

    const ushort* wihbL[2] = {wihb0, wihb1};
    const ushort* whhbL[2] = {whhb0, whhb1};
    const float*  bsumL[2] = {bsum0, bsum1};

    for (int L = 0; L < 2; ++L) {
        hipMemsetAsync(hbuf, 0, 262144, stream);
        const ushort* Abase = (L == 0) ? xg : ys0;
        ushort* ysout = (L == 0) ? ys0 : nullptr;
        for (int ch = 0; ch < 4; ++ch) {
            inproj_mfma<<<dim3(32, 32), 256, 0, stream>>>(
                Abase, wihbL[L], bsumL[L], xp, ch * 4096);
            lstm_persist<<<128, 256, 0, stream>>>(
                whhbL[L], xp, hbuf, cbuf, ysout, out, flags, ch * 64, 64, L);
        }
    }
}

// Round 5
// 4504.955 us; speedup vs baseline: 2.8513x; 1.2552x over previous
//
#include <hip/hip_runtime.h>
#include <hip/hip_bf16.h>

typedef __attribute__((ext_vector_type(8))) short bf16x8;
typedef __attribute__((ext_vector_type(4))) float f32x4;

__device__ __forceinline__ ushort f2b(float f) {
    union { float f; unsigned u; } v; v.f = f;
    unsigned r = v.u + 0x7FFFu + ((v.u >> 16) & 1u);
    return (ushort)(r >> 16);
}
__device__ __forceinline__ float b2f(ushort u) {
    union { unsigned u; float f; } v; v.u = ((unsigned)u) << 16;
    return v.f;
}
__device__ __forceinline__ float sigm(float x) {
    return 1.f / (1.f + __expf(-x));
}

// Coherent (L2-shared-allocate, device-visible) load/store.
#define HLOAD(dst, p, off) \
    asm volatile("global_load_dwordx4 %0, %1, off offset:" #off " sc0 sc1" \
                 : "=v"(dst) : "v"(p))
#define HSTORE(p, v) \
    asm volatile("global_store_dword %0, %1, off sc0 sc1" \
                 :: "v"(p), "v"(v) : "memory")

// ---------------------------------------------------------------------------
// prep_weights: f32 -> bf16 weight conversion + bias sum (b_ih + b_hh).
// ---------------------------------------------------------------------------
__global__ __launch_bounds__(256) void prep_weights(
    const float* __restrict__ wih0, const float* __restrict__ whh0,
    const float* __restrict__ bih0, const float* __restrict__ bhh0,
    const float* __restrict__ wih1, const float* __restrict__ whh1,
    const float* __restrict__ bih1, const float* __restrict__ bhh1,
    ushort* __restrict__ wih0b, ushort* __restrict__ whh0b,
    ushort* __restrict__ wih1b, ushort* __restrict__ whh1b,
    float* __restrict__ bsum0, float* __restrict__ bsum1)
{
    const int i = blockIdx.x * 256 + threadIdx.x;
    const int e = i * 4;
    float4 v;
    v = *(const float4*)&wih0[e];
    *(ushort4*)&wih0b[e] = make_ushort4(f2b(v.x), f2b(v.y), f2b(v.z), f2b(v.w));
    v = *(const float4*)&whh0[e];
    *(ushort4*)&whh0b[e] = make_ushort4(f2b(v.x), f2b(v.y), f2b(v.z), f2b(v.w));
    v = *(const float4*)&wih1[e];
    *(ushort4*)&wih1b[e] = make_ushort4(f2b(v.x), f2b(v.y), f2b(v.z), f2b(v.w));
    v = *(const float4*)&whh1[e];
    *(ushort4*)&whh1b[e] = make_ushort4(f2b(v.x), f2b(v.y), f2b(v.z), f2b(v.w));
    if (i < 1024) {
        const int b4 = i * 4;
        float4 a0 = *(const float4*)&bih0[b4];
        float4 b0 = *(const float4*)&bhh0[b4];
        *(float4*)&bsum0[b4] = make_float4(a0.x + b0.x, a0.y + b0.y, a0.z + b0.z, a0.w + b0.w);
        float4 a1 = *(const float4*)&bih1[b4];
        float4 b1 = *(const float4*)&bhh1[b4];
        *(float4*)&bsum1[b4] = make_float4(a1.x + b1.x, a1.y + b1.y, a1.z + b1.z, a1.w + b1.w);
    }
}

// ---------------------------------------------------------------------------
// gather_x: xg[row][:] = bf16(emb[idx[row]][:]); row = t*64+b, 16384 rows.
// ---------------------------------------------------------------------------
__global__ __launch_bounds__(256) void gather_x(
    const int* __restrict__ idx, const float* __restrict__ emb,
    ushort* __restrict__ xg)
{
    const int row = blockIdx.x;
    const int c = threadIdx.x;
    const int v = idx[row];
    const float4 f = *(const float4*)&emb[(size_t)v * 1024u + c * 4];
    *(ushort4*)&xg[(size_t)row * 1024u + c * 4] =
        make_ushort4(f2b(f.x), f2b(f.y), f2b(f.z), f2b(f.w));
}

// ---------------------------------------------------------------------------
// inproj_mfma: xp[m][g] = sum_k A[mbase+m][k]*W[g][k] + bsum[g]  (bf16 out)
// 128x128 tile, 4 waves x 64x64, 16x16x32 bf16 MFMA.
// ---------------------------------------------------------------------------
__global__ __launch_bounds__(256) void inproj_mfma(
    const ushort* __restrict__ A, const ushort* __restrict__ W,
    const float* __restrict__ bsum, ushort* __restrict__ xpout, int mbase)
{
    __shared__ ushort As[128][72];
    __shared__ ushort Bsh[128][72];
    const int tid = threadIdx.x;
    const int wv = tid >> 6, lane = tid & 63;
    const int l15 = lane & 15, l4 = lane >> 4;
    const int m0 = blockIdx.y * 128, n0 = blockIdx.x * 128;
    const int wm = (wv & 1) * 64, wn = (wv >> 1) * 64;

    f32x4 acc[4][4];
    #pragma unroll
    for (int i = 0; i < 4; ++i)
        #pragma unroll
        for (int j = 0; j < 4; ++j) acc[i][j] = (f32x4){0.f, 0.f, 0.f, 0.f};

    for (int k0 = 0; k0 < 1024; k0 += 64) {
        __syncthreads();
        #pragma unroll
        for (int s4 = 0; s4 < 4; ++s4) {
            const int s = tid + s4 * 256;
            const int row = s >> 3, c8 = (s & 7) * 8;
            *(bf16x8*)&As[row][c8] =
                *(const bf16x8*)&A[(size_t)(mbase + m0 + row) * 1024u + k0 + c8];
            *(bf16x8*)&Bsh[row][c8] =
                *(const bf16x8*)&W[(size_t)(n0 + row) * 1024u + k0 + c8];
        }
        __syncthreads();
        #pragma unroll
        for (int kk = 0; kk < 2; ++kk) {
            bf16x8 af[4], bfr[4];
            #pragma unroll
            for (int i = 0; i < 4; ++i) {
                af[i]  = *(const bf16x8*)&As[wm + i * 16 + l15][kk * 32 + l4 * 8];
                bfr[i] = *(const bf16x8*)&Bsh[wn + i * 16 + l15][kk * 32 + l4 * 8];
            }
            #pragma unroll
            for (int i = 0; i < 4; ++i)
                #pragma unroll
                for (int j = 0; j < 4; ++j)
                    acc[i][j] = __builtin_amdgcn_mfma_f32_16x16x32_bf16(
                        af[i], bfr[j], acc[i][j], 0, 0, 0);
        }
    }
    #pragma unroll
    for (int i = 0; i < 4; ++i) {
        const int m = m0 + wm + i * 16 + l4 * 4;
        #pragma unroll
        for (int j = 0; j < 4; ++j) {
            const int g = n0 + wn + j * 16 + l15;
            const float bs = bsum[g];
            #pragma unroll
            for (int r = 0; r < 4; ++r)
                xpout[(size_t)(m + r) * 4096u + g] = f2b(acc[i][j][r] + bs);
        }
    }
}

// ---------------------------------------------------------------------------
// lstm_persist: 64 timesteps, 128 blocks x 256 thr (4 waves).
// Block owns hc slice [bid*8, bid*8+8): 32 gate rows, weights in LDS.
// Wave wv = K-slice [256wv, 256wv+256), produced by blocks [32wv, 32wv+32).
// PER-WAVE sync: wave polls only its 32 producer flags, loads h (sc0 sc1),
// MFMAs; block re-converges at the LDS reduce. Union of 4 waves' polls
// = all 128 blocks >= step, so ping-pong WAW safety is preserved by the
// pre-store __syncthreads. ys/outHC stores are AFTER the flag signal.
// flags are globally monotonic: flag[b] = layer*256 + steps_done.
// ---------------------------------------------------------------------------
__global__ __launch_bounds__(256) void lstm_persist(
    const ushort* __restrict__ Whh,   // bf16 [4096][1024]
    const ushort* __restrict__ xp,    // bf16 [4096 m][4096 g] chunk rows
    ushort* __restrict__ hbuf,        // bf16 [2][64][1024] ping-pong
    float* __restrict__ cbuf,         // f32 [64][1024]
    ushort* __restrict__ ys,          // bf16 [16384][1024] or null
    float* __restrict__ outHC,        // h0,h1,c0,c1 each 64x1024 f32
    unsigned* __restrict__ flags,     // [128] monotonic step flags
    int t0, int nt, int layer)
{
    __shared__ ushort Ws[32][1032];           // 66 KB, row = hcl*4+q
    __shared__ float red[4][4][2][64][4];     // 32 KB
    __shared__ float gs[4][16][33];           // 8.4 KB

    const int tid = threadIdx.x;
    const int wv = tid >> 6, lane = tid & 63;
    const int l15 = lane & 15, l4 = lane >> 4;
    const int bid = blockIdx.x;
    const int hc0 = bid * 8;

    // stage weights: LDS row = hcl*4+q  <->  g = q*1024 + hc0 + hcl
    for (int s = tid; s < 32 * 128; s += 256) {
        const int row = s >> 7, c8 = (s & 127) * 8;
        const int g = (row & 3) * 1024 + hc0 + (row >> 2);
        *(bf16x8*)&Ws[row][c8] = *(const bf16x8*)&Whh[(size_t)g * 1024u + c8];
    }

    // pointwise ownership: pb = wv*16 + (lane>>2), hc pair pp = lane&3
    const int pb = wv * 16 + (lane >> 2);
    const int pp = lane & 3;
    float cs[2];
    if (t0 == 0) { cs[0] = cs[1] = 0.f; }
    else {
        float2 c2 = *(const float2*)&cbuf[(size_t)pb * 1024u + hc0 + 2 * pp];
        cs[0] = c2.x; cs[1] = c2.y;
    }
    __syncthreads();

    const int kbase = wv * 256;
    const unsigned* xpu = (const unsigned*)xp;
    const int pl = wv * 32 + (lane & 31);     // producer flag this lane polls

    for (int ts = 0; ts < nt; ++ts) {
        const int t = t0 + ts;                          // layer-local step
        const unsigned need = (unsigned)(layer * 256 + t); // input state id
        const ushort* hr = hbuf + (size_t)(t & 1) * 65536u;

        // xp prefetch first (no cross-block dependency; latency overlaps poll)
        unsigned xq[4];
        #pragma unroll
        for (int q = 0; q < 4; ++q)
            xq[q] = xpu[(size_t)(ts * 64 + pb) * 2048u + q * 512 + (hc0 >> 1) + pp];

        // per-wave poll: only this wave's 32 K-slice producers
        for (;;) {
            const unsigned f = __hip_atomic_load(&flags[pl], __ATOMIC_RELAXED, __HIP_MEMORY_SCOPE_AGENT);
            if (__all(f >= need)) break;
            __builtin_amdgcn_s_sleep(1);
        }

        // coherent h prefetch: 32 fragments (M=64 x K=256 wave slice)
        bf16x8 hf[8][4];
        const ushort* rb[4];
        #pragma unroll
        for (int i = 0; i < 4; ++i)
            rb[i] = hr + (size_t)(i * 16 + l15) * 1024u + kbase + l4 * 8;
        #pragma unroll
        for (int i = 0; i < 4; ++i) {
            HLOAD(hf[0][i], rb[i], 0);
            HLOAD(hf[1][i], rb[i], 64);
            HLOAD(hf[2][i], rb[i], 128);
            HLOAD(hf[3][i], rb[i], 192);
            HLOAD(hf[4][i], rb[i], 256);
            HLOAD(hf[5][i], rb[i], 320);
            HLOAD(hf[6][i], rb[i], 384);
            HLOAD(hf[7][i], rb[i], 448);
        }
        asm volatile("s_waitcnt vmcnt(0)" ::: "memory");
        __builtin_amdgcn_sched_barrier(0);   // keep MFMAs below the wait

        f32x4 acc[4][2];
        #pragma unroll
        for (int i = 0; i < 4; ++i) {
            acc[i][0] = (f32x4){0.f, 0.f, 0.f, 0.f};
            acc[i][1] = (f32x4){0.f, 0.f, 0.f, 0.f};
        }
        #pragma unroll
        for (int kk = 0; kk < 8; ++kk) {
            const int k = kbase + kk * 32 + l4 * 8;
            bf16x8 bf0 = *(const bf16x8*)&Ws[l15][k];
            bf16x8 bf1 = *(const bf16x8*)&Ws[16 + l15][k];
            #pragma unroll
            for (int i = 0; i < 4; ++i) {
                acc[i][0] = __builtin_amdgcn_mfma_f32_16x16x32_bf16(hf[kk][i], bf0, acc[i][0], 0, 0, 0);
                acc[i][1] = __builtin_amdgcn_mfma_f32_16x16x32_bf16(hf[kk][i], bf1, acc[i][1], 0, 0, 0);
            }
        }

        // cross-wave K reduce: wave wv keeps m-tile wv
        #pragma unroll
        for (int i = 0; i < 4; ++i) {
            if (i != wv) {
                *(f32x4*)&red[i][wv][0][lane][0] = acc[i][0];
                *(f32x4*)&red[i][wv][1][lane][0] = acc[i][1];
            }
        }
        __syncthreads();                     // block reconverges here
        f32x4 fin0 = (f32x4){0.f,0.f,0.f,0.f}, fin1 = (f32x4){0.f,0.f,0.f,0.f};
        #pragma unroll
        for (int i = 0; i < 4; ++i)
            if (i == wv) { fin0 = acc[i][0]; fin1 = acc[i][1]; }
        #pragma unroll
        for (int src = 0; src < 4; ++src) {
            if (src != wv) {
                fin0 += *(const f32x4*)&red[wv][src][0][lane][0];
                fin1 += *(const f32x4*)&red[wv][src][1][lane][0];
            }
        }

        // wave-local gate-sum bounce: gs[wv][m_loc][gate_row]
        #pragma unroll
        for (int r = 0; r < 4; ++r) {
            gs[wv][l4 * 4 + r][l15]      = fin0[r];
            gs[wv][l4 * 4 + r][16 + l15] = fin1[r];
        }

        // pointwise: thread owns (pb, hc = hc0 + 2*pp + {0,1})
        ushort* hw = hbuf + (size_t)((t + 1) & 1) * 65536u;
        float hv[2];
        #pragma unroll
        for (int d = 0; d < 2; ++d) {
            const int grow = (2 * pp + d) * 4;
            const float g0 = gs[wv][lane >> 2][grow + 0] + b2f((ushort)(d ? (xq[0] >> 16) : (xq[0] & 0xffff)));
            const float g1 = gs[wv][lane >> 2][grow + 1] + b2f((ushort)(d ? (xq[1] >> 16) : (xq[1] & 0xffff)));
            const float g2 = gs[wv][lane >> 2][grow + 2] + b2f((ushort)(d ? (xq[2] >> 16) : (xq[2] & 0xffff)));
            const float g3 = gs[wv][lane >> 2][grow + 3] + b2f((ushort)(d ? (xq[3] >> 16) : (xq[3] & 0xffff)));
            const float ig = sigm(g0), fg = sigm(g1);
            const float gg = tanhf(g2), og = sigm(g3);
            const float c = fg * cs[d] + ig * gg;
            hv[d] = og * tanhf(c);
            cs[d] = c;
        }
        const unsigned hpack = (unsigned)f2b(hv[0]) | ((unsigned)f2b(hv[1]) << 16);
        unsigned* hwp = (unsigned*)(hw + (size_t)pb * 1024u + hc0 + 2 * pp);
        HSTORE(hwp, hpack);
        // drain exactly the coherent h-store (everything else already waited)
        asm volatile("s_waitcnt vmcnt(0)" ::: "memory");
        __syncthreads();                     // all 4 waves' h-stores drained
        if (tid == 0)
            __hip_atomic_store(&flags[bid], need + 1, __ATOMIC_RELAXED, __HIP_MEMORY_SCOPE_AGENT);

        // deferred cached stores (consumed only by later dispatches)
        if (ys)
            *(unsigned*)(ys + (size_t)(t * 64 + pb) * 1024u + hc0 + 2 * pp) = hpack;
        if (t == 255) {
            #pragma unroll
            for (int d = 0; d < 2; ++d) {
                const int hc = hc0 + 2 * pp + d;
                outHC[(size_t)layer * 65536u + (size_t)pb * 1024u + hc] = hv[d];
                outHC[131072u + (size_t)layer * 65536u + (size_t)pb * 1024u + hc] = cs[d];
            }
        }
    }

    *(float2*)&cbuf[(size_t)pb * 1024u + hc0 + 2 * pp] = make_float2(cs[0], cs[1]);
}

// ---------------------------------------------------------------------------
extern "C" void kernel_launch(void* const* d_in, const int* in_sizes, int n_in,
                              void* d_out, int out_size, void* d_ws, size_t ws_size,
                              hipStream_t stream) {
    (void)in_sizes; (void)n_in; (void)out_size; (void)ws_size;
    const int*   idx  = (const int*)d_in[0];
    const float* emb  = (const float*)d_in[1];
    const float* wih[2] = {(const float*)d_in[2], (const float*)d_in[6]};
    const float* whh[2] = {(const float*)d_in[3], (const float*)d_in[7]};
    const float* bih[2] = {(const float*)d_in[4], (const float*)d_in[8]};
    const float* bhh[2] = {(const float*)d_in[5], (const float*)d_in[9]};
    float* out = (float*)d_out;

    char* p = (char*)d_ws;
    ushort* xg    = (ushort*)p;  p += 33554432;   // 16384x1024 bf16
    ushort* ys0   = (ushort*)p;  p += 33554432;   // 16384x1024 bf16
    ushort* wihb0 = (ushort*)p;  p += 8388608;
    ushort* whhb0 = (ushort*)p;  p += 8388608;
    ushort* wihb1 = (ushort*)p;  p += 8388608;
    ushort* whhb1 = (ushort*)p;  p += 8388608;
    ushort* xp    = (ushort*)p;  p += 33554432;   // [4096 m][4096 g] bf16 chunk
    ushort* hbuf  = (ushort*)p;  p += 262144;     // 2x64x1024 bf16
    float*  cbuf  = (float*)p;   p += 262144;     // 64x1024 f32
    float*  bsum0 = (float*)p;   p += 16384;
    float*  bsum1 = (float*)p;   p += 16384;
    unsigned* flags = (unsigned*)p;               // 128 x u32

    hipMemsetAsync(flags, 0, 512, stream);
    prep_weights<<<4096, 256, 0, stream>>>(
        wih[0], whh[0], bih[0], bhh[0], wih[1], whh[1], bih[1], bhh[1],
        wihb0, whhb0, wihb1, whhb1, bsum0, bsum1);
    gather_x<<<16384, 256, 0, stream>>>(idx, emb, xg);

    const ushort* wihbL[2] = {wihb0, wihb1};
    const ushort* whhbL[2] = {whhb0, whhb1};
    const float*  bsumL[2] = {bsum0, bsum1};

    for (int L = 0; L < 2; ++L) {
        hipMemsetAsync(hbuf, 0, 262144, stream);
        const ushort* Abase = (L == 0) ? xg : ys0;
        ushort* ysout = (L == 0) ? ys0 : nullptr;
        for (int ch = 0; ch < 4; ++ch) {
            inproj_mfma<<<dim3(32, 32), 256, 0, stream>>>(
                Abase, wihbL[L], bsumL[L], xp, ch * 4096);
            lstm_persist<<<128, 256, 0, stream>>>(
                whhbL[L], xp, hbuf, cbuf, ysout, out, flags, ch * 64, 64, L);
        }
    }
}